// Round 1
// baseline (4965.739 us; speedup 1.0000x reference)
//
#include <hip/hip_runtime.h>
#include <hip/hip_bf16.h>

typedef unsigned short u16;   // bf16 bits

__device__ __forceinline__ float bu2f(u16 u) {
    return __uint_as_float(((unsigned)u) << 16);
}
__device__ __forceinline__ u16 f2bu(float f) {   // RNE f32->bf16
    unsigned u = __float_as_uint(f);
    u += 0x7fffu + ((u >> 16) & 1u);
    return (u16)(u >> 16);
}

// ---------------------------------------------------------------------------
// K1: stage-2 block linear. x (B,32,32,3) f32 NHWC -> xf (B,32,32,3) bf16 NHWC
// Per 4x4x3 block: out[o] = sum_k W[o,k]*blk[k], k,o = ir*12+jc*3+c.
// (The reference's permutation exactly undoes the block flattening.)
// ---------------------------------------------------------------------------
__global__ __launch_bounds__(256) void k_stage2(
    const float* __restrict__ x, const float* __restrict__ W,
    const int* __restrict__ stage, u16* __restrict__ xf)
{
    __shared__ float xl[3072];
    __shared__ float wl[2304];
    const int b = blockIdx.x, t = threadIdx.x;
    const float* xp = x + (size_t)b * 3072;
    for (int i = t; i < 3072; i += 256) xl[i] = xp[i];
    for (int i = t; i < 2304; i += 256) wl[i] = W[i];
    __syncthreads();
    u16* op = xf + (size_t)b * 3072;
    if (stage[0] != 2) {
        for (int i = t; i < 3072; i += 256) op[i] = f2bu(xl[i]);
        return;
    }
    #pragma unroll
    for (int i = 0; i < 12; ++i) {
        int e = i * 256 + t;
        int h = e / 96, rem = e - h * 96;
        int w = rem / 3, c = rem - w * 3;
        int ib = h >> 2, ir = h & 3, jb = w >> 2, jc = w & 3;
        const float* wrow = &wl[(ir * 12 + jc * 3 + c) * 48];
        const float* xblk = &xl[(ib * 4) * 96 + (jb * 4) * 3];
        float acc = 0.f;
        #pragma unroll
        for (int kr = 0; kr < 4; ++kr)
            #pragma unroll
            for (int kc = 0; kc < 4; ++kc)
                #pragma unroll
                for (int cc = 0; cc < 3; ++cc)
                    acc += wrow[kr * 12 + kc * 3 + cc] * xblk[kr * 96 + kc * 3 + cc];
        op[e] = f2bu(acc);
    }
}

// ---------------------------------------------------------------------------
// K2: conv1 3->32 (3x3 SAME) + ReLU + maxpool2.
// xf (B,32,32,3) bf16 -> o1 (B,16,16,32) bf16 NHWC.  One WG per image.
// Thread: 8 oc x one pooled pos (2x2 prepool) per iter, 4 iters.
// ---------------------------------------------------------------------------
__global__ __launch_bounds__(256) void k_conv1(
    const u16* __restrict__ xf, const float* __restrict__ cw,
    const float* __restrict__ cb, u16* __restrict__ o1)
{
    __shared__ float img[3 * 34 * 34];   // [c][h+1][w+1], zero halo
    __shared__ float wl[864];            // [oc][c*9+kh*3+kw]
    const int b = blockIdx.x, t = threadIdx.x;
    for (int i = t; i < 3 * 34 * 34; i += 256) img[i] = 0.f;
    for (int i = t; i < 864; i += 256) wl[i] = cw[i];
    __syncthreads();
    const u16* xp = xf + (size_t)b * 3072;
    for (int e = t; e < 3072; e += 256) {
        int h = e / 96, rem = e - h * 96;
        int w = rem / 3, c = rem - w * 3;
        img[c * 1156 + (h + 1) * 34 + (w + 1)] = bu2f(xp[e]);
    }
    __syncthreads();
    u16* op = o1 + (size_t)b * 8192;
    const int oc0 = (t & 3) * 8;
    const int q = t >> 2;
    #pragma unroll
    for (int i = 0; i < 4; ++i) {
        const int pp = i * 64 + q;          // pooled position 0..255
        const int ph = pp >> 4, pw = pp & 15;
        float acc[2][2][8];
        #pragma unroll
        for (int dh = 0; dh < 2; ++dh)
            #pragma unroll
            for (int dw = 0; dw < 2; ++dw)
                #pragma unroll
                for (int o = 0; o < 8; ++o) acc[dh][dw][o] = 0.f;
        #pragma unroll
        for (int c = 0; c < 3; ++c)
            #pragma unroll
            for (int kh = 0; kh < 3; ++kh)
                #pragma unroll
                for (int kw = 0; kw < 3; ++kw) {
                    float iv[2][2];
                    #pragma unroll
                    for (int dh = 0; dh < 2; ++dh)
                        #pragma unroll
                        for (int dw = 0; dw < 2; ++dw)
                            iv[dh][dw] = img[c * 1156 + (2 * ph + dh + kh) * 34 + (2 * pw + dw + kw)];
                    #pragma unroll
                    for (int o = 0; o < 8; ++o) {
                        float wv = wl[(oc0 + o) * 27 + c * 9 + kh * 3 + kw];
                        #pragma unroll
                        for (int dh = 0; dh < 2; ++dh)
                            #pragma unroll
                            for (int dw = 0; dw < 2; ++dw)
                                acc[dh][dw][o] += iv[dh][dw] * wv;
                    }
                }
        #pragma unroll
        for (int o = 0; o < 8; ++o) {
            float bias = cb[oc0 + o];
            float m = fmaxf(acc[0][0][o] + bias, 0.f);
            m = fmaxf(m, fmaxf(acc[0][1][o] + bias, 0.f));
            m = fmaxf(m, fmaxf(acc[1][0][o] + bias, 0.f));
            m = fmaxf(m, fmaxf(acc[1][1][o] + bias, 0.f));
            op[pp * 32 + oc0 + o] = f2bu(m);
        }
    }
}

// ---------------------------------------------------------------------------
// K3: conv2 32->64 + ReLU + maxpool2. o1 (B,16,16,32) -> o2 (B,8,8,64) bf16.
// Grid (B, 2): blockIdx.y = 32-oc block. Thread: 8 oc x 1 pooled pos.
// Input LDS [ic][18][19] bf16 (zero halo); weights LDS f32 [32][288].
// ---------------------------------------------------------------------------
__global__ __launch_bounds__(256) void k_conv2(
    const u16* __restrict__ o1, const float* __restrict__ cw,
    const float* __restrict__ cb, u16* __restrict__ o2)
{
    __shared__ u16 inl[32 * 18 * 19];
    __shared__ float wl[32 * 288];
    const int b = blockIdx.x, t = threadIdx.x;
    const int ocb = blockIdx.y * 32;
    for (int i = t; i < 32 * 18 * 19; i += 256) inl[i] = 0;
    for (int i = t; i < 32 * 288; i += 256) wl[i] = cw[ocb * 288 + i];
    __syncthreads();
    const u16* ip = o1 + (size_t)b * 8192;
    for (int e = t; e < 8192; e += 256) {
        int h = e >> 9, w = (e >> 5) & 15, ic = e & 31;
        inl[ic * 342 + (h + 1) * 19 + (w + 1)] = ip[e];
    }
    __syncthreads();
    const int pos = t & 63, ph = pos >> 3, pw = pos & 7;
    const int oc0 = (t >> 6) * 8;        // wave-uniform -> weight reads broadcast
    float acc[2][2][8];
    #pragma unroll
    for (int dh = 0; dh < 2; ++dh)
        #pragma unroll
        for (int dw = 0; dw < 2; ++dw)
            #pragma unroll
            for (int o = 0; o < 8; ++o) acc[dh][dw][o] = 0.f;
    for (int ic = 0; ic < 32; ++ic) {
        #pragma unroll
        for (int kh = 0; kh < 3; ++kh)
            #pragma unroll
            for (int kw = 0; kw < 3; ++kw) {
                float iv[2][2];
                #pragma unroll
                for (int dh = 0; dh < 2; ++dh)
                    #pragma unroll
                    for (int dw = 0; dw < 2; ++dw)
                        iv[dh][dw] = bu2f(inl[ic * 342 + (2 * ph + kh + dh) * 19 + (2 * pw + kw + dw)]);
                #pragma unroll
                for (int o = 0; o < 8; ++o) {
                    float wv = wl[(oc0 + o) * 288 + ic * 9 + kh * 3 + kw];
                    #pragma unroll
                    for (int dh = 0; dh < 2; ++dh)
                        #pragma unroll
                        for (int dw = 0; dw < 2; ++dw)
                            acc[dh][dw][o] += iv[dh][dw] * wv;
                }
            }
    }
    u16* op = o2 + (size_t)b * 4096 + (ph * 8 + pw) * 64 + ocb + oc0;
    #pragma unroll
    for (int o = 0; o < 8; ++o) {
        float bias = cb[ocb + oc0 + o];
        float m = fmaxf(acc[0][0][o] + bias, 0.f);
        m = fmaxf(m, fmaxf(acc[0][1][o] + bias, 0.f));
        m = fmaxf(m, fmaxf(acc[1][0][o] + bias, 0.f));
        m = fmaxf(m, fmaxf(acc[1][1][o] + bias, 0.f));
        op[o] = f2bu(m);
    }
}

// ---------------------------------------------------------------------------
// K4: conv3 64->128 + ReLU + maxpool2. o2 (B,8,8,64) -> o3 (B,4,4,128) bf16.
// WG = 2 images; 4 chunks of 32 oc (weights restaged per chunk, bf16 LDS).
// Thread: 4 oc x 1 pooled pos (2x2 prepool), per chunk.
// ---------------------------------------------------------------------------
__global__ __launch_bounds__(256) void k_conv3(
    const u16* __restrict__ o2, const float* __restrict__ cw,
    const float* __restrict__ cb, u16* __restrict__ o3)
{
    __shared__ u16 inl[2 * 64 * 10 * 10];  // [u][ic][h+1][w+1]
    __shared__ u16 wl[32 * 576];           // [ocl][ic*9+kh*3+kw] bf16
    const int b0 = blockIdx.x * 2, t = threadIdx.x;
    for (int i = t; i < 2 * 64 * 100; i += 256) inl[i] = 0;
    __syncthreads();
    #pragma unroll
    for (int u = 0; u < 2; ++u) {
        const u16* ip = o2 + (size_t)(b0 + u) * 4096;
        for (int e = t; e < 4096; e += 256) {
            int h = e >> 9, w = (e >> 6) & 7, ic = e & 63;
            inl[((u * 64 + ic) * 10 + h + 1) * 10 + (w + 1)] = ip[e];
        }
    }
    const int pos = t & 31, uu = pos >> 4, pp = pos & 15;
    const int ph = pp >> 2, pw = pp & 3;
    const int og = t >> 5;                 // 0..7, 4 oc each
    u16* op = o3 + (size_t)(b0 + uu) * 2048 + (ph * 4 + pw) * 128 + og * 4;
    for (int cc = 0; cc < 4; ++cc) {
        __syncthreads();                   // also fences input fill at cc=0
        for (int i = t; i < 32 * 576; i += 256) wl[i] = f2bu(cw[cc * 18432 + i]);
        __syncthreads();
        float acc[2][2][4];
        #pragma unroll
        for (int dh = 0; dh < 2; ++dh)
            #pragma unroll
            for (int dw = 0; dw < 2; ++dw)
                #pragma unroll
                for (int o = 0; o < 4; ++o) acc[dh][dw][o] = 0.f;
        for (int ic = 0; ic < 64; ++ic) {
            #pragma unroll
            for (int kh = 0; kh < 3; ++kh)
                #pragma unroll
                for (int kw = 0; kw < 3; ++kw) {
                    float iv[2][2];
                    #pragma unroll
                    for (int dh = 0; dh < 2; ++dh)
                        #pragma unroll
                        for (int dw = 0; dw < 2; ++dw)
                            iv[dh][dw] = bu2f(inl[((uu * 64 + ic) * 10 + 2 * ph + kh + dh) * 10 + 2 * pw + kw + dw]);
                    #pragma unroll
                    for (int o = 0; o < 4; ++o) {
                        float wv = bu2f(wl[(og * 4 + o) * 576 + ic * 9 + kh * 3 + kw]);
                        #pragma unroll
                        for (int dh = 0; dh < 2; ++dh)
                            #pragma unroll
                            for (int dw = 0; dw < 2; ++dw)
                                acc[dh][dw][o] += iv[dh][dw] * wv;
                    }
                }
        }
        #pragma unroll
        for (int o = 0; o < 4; ++o) {
            float bias = cb[cc * 32 + og * 4 + o];
            float m = fmaxf(acc[0][0][o] + bias, 0.f);
            m = fmaxf(m, fmaxf(acc[0][1][o] + bias, 0.f));
            m = fmaxf(m, fmaxf(acc[1][0][o] + bias, 0.f));
            m = fmaxf(m, fmaxf(acc[1][1][o] + bias, 0.f));
            op[cc * 32 + o] = f2bu(m);
        }
    }
}

// ---------------------------------------------------------------------------
// K5: fc (2048->10, NCHW flatten c*16+h*4+w) + log_softmax. One wave/image.
// ---------------------------------------------------------------------------
__global__ __launch_bounds__(256) void k_fc(
    const u16* __restrict__ o3, const float* __restrict__ fw,
    const float* __restrict__ fb, float* __restrict__ out)
{
    const int b = blockIdx.x * 4 + (threadIdx.x >> 6);
    const int lane = threadIdx.x & 63;
    const u16* xp = o3 + (size_t)b * 2048;
    float xr[32];
    #pragma unroll
    for (int i = 0; i < 32; ++i) {
        int kk = lane + i * 64;            // NCHW flat index = c*16 + h*4 + w
        int c = kk >> 4, h = (kk >> 2) & 3, w = kk & 3;
        xr[i] = bu2f(xp[h * 512 + w * 128 + c]);   // o3 is NHWC [h][w][c]
    }
    float lg[10];
    #pragma unroll
    for (int o = 0; o < 10; ++o) {
        const float* wr = fw + (size_t)o * 2048;
        float s = 0.f;
        #pragma unroll
        for (int i = 0; i < 32; ++i) s += xr[i] * wr[lane + i * 64];
        #pragma unroll
        for (int d = 32; d > 0; d >>= 1) s += __shfl_xor(s, d);
        lg[o] = s + fb[o];
    }
    float m = lg[0];
    #pragma unroll
    for (int o = 1; o < 10; ++o) m = fmaxf(m, lg[o]);
    float den = 0.f;
    #pragma unroll
    for (int o = 0; o < 10; ++o) den += expf(lg[o] - m);
    float lse = logf(den);
    if (lane < 10) {
        float v = lg[0];
        #pragma unroll
        for (int o = 1; o < 10; ++o) v = (lane == o) ? lg[o] : v;
        out[(size_t)b * 10 + lane] = v - m - lse;
    }
}

extern "C" void kernel_launch(void* const* d_in, const int* in_sizes, int n_in,
                              void* d_out, int out_size, void* d_ws, size_t ws_size,
                              hipStream_t stream)
{
    const float* x    = (const float*)d_in[0];
    const float* Wlin = (const float*)d_in[1];
    const float* c1w  = (const float*)d_in[2];
    const float* c1b  = (const float*)d_in[3];
    const float* c2w  = (const float*)d_in[4];
    const float* c2b  = (const float*)d_in[5];
    const float* c3w  = (const float*)d_in[6];
    const float* c3b  = (const float*)d_in[7];
    const float* fw   = (const float*)d_in[8];
    const float* fb   = (const float*)d_in[9];
    const int* stage  = (const int*)d_in[10];
    float* out = (float*)d_out;

    const int B = in_sizes[0] / 3072;      // 8192

    // ws regions (bf16): xf B*3072 | o1 B*8192 | o2 B*4096 ; o3 reuses xf slot.
    char* ws = (char*)d_ws;
    u16* xf = (u16*)ws;                                    // B*6144 bytes
    u16* o1 = (u16*)(ws + (size_t)B * 6144);               // B*16384 bytes
    u16* o2 = (u16*)(ws + (size_t)B * 22528);              // B*8192 bytes
    u16* o3 = (u16*)ws;                                    // reuse xf (dead after conv1)

    k_stage2<<<B, 256, 0, stream>>>(x, Wlin, stage, xf);
    k_conv1 <<<B, 256, 0, stream>>>(xf, c1w, c1b, o1);
    k_conv2 <<<dim3(B, 2), 256, 0, stream>>>(o1, c2w, c2b, o2);
    k_conv3 <<<B / 2, 256, 0, stream>>>(o2, c3w, c3b, o3);
    k_fc    <<<B / 4, 256, 0, stream>>>(o3, fw, fb, out);
}

// Round 2
// 944.377 us; speedup vs baseline: 5.2582x; 5.2582x over previous
//
#include <hip/hip_runtime.h>
#include <hip/hip_bf16.h>

typedef unsigned short u16;   // bf16 bits
typedef __attribute__((ext_vector_type(8))) short short8v;   // 8 bf16 (4 VGPRs)
typedef __attribute__((ext_vector_type(4))) float f32x4;

__device__ __forceinline__ float bu2f(u16 u) {
    return __uint_as_float(((unsigned)u) << 16);
}
__device__ __forceinline__ u16 f2bu(float f) {   // RNE f32->bf16
    unsigned u = __float_as_uint(f);
    u += 0x7fffu + ((u >> 16) & 1u);
    return (u16)(u >> 16);
}

// ---------------------------------------------------------------------------
// K1: stage-2 block linear. x (B,32,32,3) f32 NHWC -> xf (B,32,32,3) bf16 NHWC
// ---------------------------------------------------------------------------
__global__ __launch_bounds__(256) void k_stage2(
    const float* __restrict__ x, const float* __restrict__ W,
    const int* __restrict__ stage, u16* __restrict__ xf)
{
    __shared__ float xl[3072];
    __shared__ float wl[2304];
    const int b = blockIdx.x, t = threadIdx.x;
    const float* xp = x + (size_t)b * 3072;
    for (int i = t; i < 3072; i += 256) xl[i] = xp[i];
    for (int i = t; i < 2304; i += 256) wl[i] = W[i];
    __syncthreads();
    u16* op = xf + (size_t)b * 3072;
    if (stage[0] != 2) {
        for (int i = t; i < 3072; i += 256) op[i] = f2bu(xl[i]);
        return;
    }
    #pragma unroll
    for (int i = 0; i < 12; ++i) {
        int e = i * 256 + t;
        int h = e / 96, rem = e - h * 96;
        int w = rem / 3, c = rem - w * 3;
        int ib = h >> 2, ir = h & 3, jb = w >> 2, jc = w & 3;
        const float* wrow = &wl[(ir * 12 + jc * 3 + c) * 48];
        const float* xblk = &xl[(ib * 4) * 96 + (jb * 4) * 3];
        float acc = 0.f;
        #pragma unroll
        for (int kr = 0; kr < 4; ++kr)
            #pragma unroll
            for (int kc = 0; kc < 4; ++kc)
                #pragma unroll
                for (int cc = 0; cc < 3; ++cc)
                    acc += wrow[kr * 12 + kc * 3 + cc] * xblk[kr * 96 + kc * 3 + cc];
        op[e] = f2bu(acc);
    }
}

// ---------------------------------------------------------------------------
// K2: conv1 3->32 (3x3 SAME) + ReLU + maxpool2 (scalar; K=27 too small for MFMA yet)
// ---------------------------------------------------------------------------
__global__ __launch_bounds__(256) void k_conv1(
    const u16* __restrict__ xf, const float* __restrict__ cw,
    const float* __restrict__ cb, u16* __restrict__ o1)
{
    __shared__ float img[3 * 34 * 34];
    __shared__ float wl[864];
    const int b = blockIdx.x, t = threadIdx.x;
    for (int i = t; i < 3 * 34 * 34; i += 256) img[i] = 0.f;
    for (int i = t; i < 864; i += 256) wl[i] = cw[i];
    __syncthreads();
    const u16* xp = xf + (size_t)b * 3072;
    for (int e = t; e < 3072; e += 256) {
        int h = e / 96, rem = e - h * 96;
        int w = rem / 3, c = rem - w * 3;
        img[c * 1156 + (h + 1) * 34 + (w + 1)] = bu2f(xp[e]);
    }
    __syncthreads();
    u16* op = o1 + (size_t)b * 8192;
    const int oc0 = (t & 3) * 8;
    const int q = t >> 2;
    #pragma unroll
    for (int i = 0; i < 4; ++i) {
        const int pp = i * 64 + q;
        const int ph = pp >> 4, pw = pp & 15;
        float acc[2][2][8];
        #pragma unroll
        for (int dh = 0; dh < 2; ++dh)
            #pragma unroll
            for (int dw = 0; dw < 2; ++dw)
                #pragma unroll
                for (int o = 0; o < 8; ++o) acc[dh][dw][o] = 0.f;
        #pragma unroll
        for (int c = 0; c < 3; ++c)
            #pragma unroll
            for (int kh = 0; kh < 3; ++kh)
                #pragma unroll
                for (int kw = 0; kw < 3; ++kw) {
                    float iv[2][2];
                    #pragma unroll
                    for (int dh = 0; dh < 2; ++dh)
                        #pragma unroll
                        for (int dw = 0; dw < 2; ++dw)
                            iv[dh][dw] = img[c * 1156 + (2 * ph + dh + kh) * 34 + (2 * pw + dw + kw)];
                    #pragma unroll
                    for (int o = 0; o < 8; ++o) {
                        float wv = wl[(oc0 + o) * 27 + c * 9 + kh * 3 + kw];
                        #pragma unroll
                        for (int dh = 0; dh < 2; ++dh)
                            #pragma unroll
                            for (int dw = 0; dw < 2; ++dw)
                                acc[dh][dw][o] += iv[dh][dw] * wv;
                    }
                }
        #pragma unroll
        for (int o = 0; o < 8; ++o) {
            float bias = cb[oc0 + o];
            float m = fmaxf(acc[0][0][o] + bias, 0.f);
            m = fmaxf(m, fmaxf(acc[0][1][o] + bias, 0.f));
            m = fmaxf(m, fmaxf(acc[1][0][o] + bias, 0.f));
            m = fmaxf(m, fmaxf(acc[1][1][o] + bias, 0.f));
            op[pp * 32 + oc0 + o] = f2bu(m);
        }
    }
}

// ---------------------------------------------------------------------------
// K-repack: conv2/conv3 weights OIHW f32 -> [oc][tap][ic] bf16, padded rows.
// w2p: [64][296] (tap*32+ic valid to 288). w3p: [128][584] (valid to 576).
// ---------------------------------------------------------------------------
__global__ __launch_bounds__(256) void k_repack(
    const float* __restrict__ c2w, const float* __restrict__ c3w,
    u16* __restrict__ w2p, u16* __restrict__ w3p)
{
    int i = blockIdx.x * 256 + threadIdx.x;
    if (i < 64 * 288) {
        int oc = i / 288, r = i - oc * 288;
        int tap = r >> 5, ic = r & 31;
        w2p[oc * 296 + r] = f2bu(c2w[(oc * 32 + ic) * 9 + tap]);
    }
    if (i < 128 * 576) {
        int oc = i / 576, r = i - oc * 576;
        int tap = r >> 6, ic = r & 63;
        w3p[oc * 584 + r] = f2bu(c3w[(oc * 64 + ic) * 9 + tap]);
    }
}

// ---------------------------------------------------------------------------
// K3: conv2 32->64 + ReLU + maxpool2, MFMA implicit GEMM.
// Per image: M=256 pos (h*16+w), N=64 oc, K=288 (tap-major, 32 ic per tap).
// 4 waves x (4 Mfrag x 4 Nfrag) of 16x16x32. Input LDS (h*18+w)*40+ic.
// ---------------------------------------------------------------------------
__global__ __launch_bounds__(256) void k_conv2m(
    const u16* __restrict__ o1, const u16* __restrict__ w2p,
    const float* __restrict__ cb, u16* __restrict__ o2)
{
    __shared__ u16 inl[12960];   // ((h)*18+w)*40 + ic ; zero halo
    __shared__ u16 wl[18944];    // [oc][296]
    const int b = blockIdx.x, t = threadIdx.x;
    uint* z = (uint*)inl;
    for (int i = t; i < 6480; i += 256) z[i] = 0u;
    for (int i = t; i < 2368; i += 256)
        *(short8v*)(&wl[i * 8]) = *(const short8v*)(&w2p[i * 8]);
    __syncthreads();
    const u16* ip = o1 + (size_t)b * 8192;
    for (int e = t; e < 1024; e += 256) {
        int ic8 = e & 3, w = (e >> 2) & 15, h = e >> 6;
        *(short8v*)(&inl[((h + 1) * 18 + (w + 1)) * 40 + ic8 * 8]) =
            *(const short8v*)(&ip[e * 8]);
    }
    __syncthreads();
    const int wv = t >> 6, lane = t & 63;
    const int lr = lane & 15, q = lane >> 4;
    f32x4 acc[4][4];
    #pragma unroll
    for (int m = 0; m < 4; ++m)
        #pragma unroll
        for (int n = 0; n < 4; ++n) acc[m][n] = (f32x4){0.f, 0.f, 0.f, 0.f};
    #pragma unroll
    for (int kh = 0; kh < 3; ++kh)
        #pragma unroll
        for (int kw = 0; kw < 3; ++kw) {
            short8v af[4], bf[4];
            #pragma unroll
            for (int m = 0; m < 4; ++m)
                af[m] = *(const short8v*)(&inl[((wv * 4 + m + kh) * 18 + lr + kw) * 40 + q * 8]);
            #pragma unroll
            for (int n = 0; n < 4; ++n)
                bf[n] = *(const short8v*)(&wl[(n * 16 + lr) * 296 + (kh * 3 + kw) * 32 + q * 8]);
            #pragma unroll
            for (int m = 0; m < 4; ++m)
                #pragma unroll
                for (int n = 0; n < 4; ++n)
                    acc[m][n] = __builtin_amdgcn_mfma_f32_16x16x32_bf16(af[m], bf[n], acc[m][n], 0, 0, 0);
        }
    // epilogue: bias+relu, 2x2 maxpool, store NHWC (8,8,64)
    u16* op = o2 + (size_t)b * 4096;
    #pragma unroll
    for (int n = 0; n < 4; ++n) {
        float bias = cb[n * 16 + lr];
        #pragma unroll
        for (int mp = 0; mp < 2; ++mp) {
            #pragma unroll
            for (int p = 0; p < 2; ++p) {
                float v = fmaxf(acc[2 * mp][n][2 * p] + bias, 0.f);
                v = fmaxf(v, fmaxf(acc[2 * mp][n][2 * p + 1] + bias, 0.f));
                v = fmaxf(v, fmaxf(acc[2 * mp + 1][n][2 * p] + bias, 0.f));
                v = fmaxf(v, fmaxf(acc[2 * mp + 1][n][2 * p + 1] + bias, 0.f));
                int hq = wv * 2 + mp, wq = 2 * q + p;
                op[(hq * 8 + wq) * 64 + n * 16 + lr] = f2bu(v);
            }
        }
    }
}

// ---------------------------------------------------------------------------
// K4: conv3 64->128 + ReLU + maxpool2, MFMA implicit GEMM.
// Grid (B/4, 2): 4 images, 64-oc chunk. M=256 (u*64+h*8+w), N=64, K=576.
// 4 waves x (4 Mfrag x 4 Nfrag); wave wv owns image u=wv.
// ---------------------------------------------------------------------------
__global__ __launch_bounds__(256) void k_conv3m(
    const u16* __restrict__ o2, const u16* __restrict__ w3p,
    const float* __restrict__ cb, u16* __restrict__ o3)
{
    __shared__ u16 inl[28800];   // (u*100 + h*10 + w)*72 + ic ; zero halo
    __shared__ u16 wl[37376];    // [ocl][584]
    const int b0 = blockIdx.x * 4, ocb = blockIdx.y * 64, t = threadIdx.x;
    uint* z = (uint*)inl;
    for (int i = t; i < 14400; i += 256) z[i] = 0u;
    const u16* wp = w3p + (size_t)ocb * 584;
    for (int i = t; i < 4672; i += 256)
        *(short8v*)(&wl[i * 8]) = *(const short8v*)(&wp[i * 8]);
    __syncthreads();
    for (int e = t; e < 2048; e += 256) {
        int u = e >> 9, rem = e & 511;
        int ic8 = rem & 7, w = (rem >> 3) & 7, h = rem >> 6;
        *(short8v*)(&inl[(u * 100 + (h + 1) * 10 + (w + 1)) * 72 + ic8 * 8]) =
            *(const short8v*)(&o2[(size_t)(b0 + u) * 4096 + rem * 8]);
    }
    __syncthreads();
    const int wv = t >> 6, lane = t & 63;
    const int lr = lane & 15, q = lane >> 4;
    const int hA = lr >> 3, wA = lr & 7;     // A-frag row -> (h,w) within image
    f32x4 acc[4][4];
    #pragma unroll
    for (int m = 0; m < 4; ++m)
        #pragma unroll
        for (int n = 0; n < 4; ++n) acc[m][n] = (f32x4){0.f, 0.f, 0.f, 0.f};
    #pragma unroll
    for (int tap = 0; tap < 9; ++tap) {
        const int kh = tap / 3, kw = tap - kh * 3;
        #pragma unroll
        for (int half = 0; half < 2; ++half) {
            short8v af[4], bf[4];
            #pragma unroll
            for (int m = 0; m < 4; ++m)
                af[m] = *(const short8v*)(&inl[(wv * 100 + (m * 2 + hA + kh) * 10 + wA + kw) * 72
                                               + half * 32 + q * 8]);
            #pragma unroll
            for (int n = 0; n < 4; ++n)
                bf[n] = *(const short8v*)(&wl[(n * 16 + lr) * 584 + tap * 64 + half * 32 + q * 8]);
            #pragma unroll
            for (int m = 0; m < 4; ++m)
                #pragma unroll
                for (int n = 0; n < 4; ++n)
                    acc[m][n] = __builtin_amdgcn_mfma_f32_16x16x32_bf16(af[m], bf[n], acc[m][n], 0, 0, 0);
        }
    }
    // epilogue: bias+relu, pool. C row r=4q+reg -> h=m*2+(q>>1), w=(q&1)*4+reg.
    #pragma unroll
    for (int n = 0; n < 4; ++n) {
        float bias = cb[ocb + n * 16 + lr];
        #pragma unroll
        for (int m = 0; m < 4; ++m) {
            #pragma unroll
            for (int p = 0; p < 2; ++p) {
                float v = fmaxf(acc[m][n][2 * p] + bias, 0.f);
                v = fmaxf(v, fmaxf(acc[m][n][2 * p + 1] + bias, 0.f));
                float v2 = fmaxf(v, __shfl_xor(v, 32));   // h-pair: q <-> q^2
                if (lane < 32) {
                    int wq = (q & 1) * 2 + p;
                    o3[(size_t)(b0 + wv) * 2048 + (m * 4 + wq) * 128 + ocb + n * 16 + lr] = f2bu(v2);
                }
            }
        }
    }
}

// ---------------------------------------------------------------------------
// K5: fc (2048->10, NCHW flatten) + log_softmax. One wave/image.
// ---------------------------------------------------------------------------
__global__ __launch_bounds__(256) void k_fc(
    const u16* __restrict__ o3, const float* __restrict__ fw,
    const float* __restrict__ fb, float* __restrict__ out)
{
    const int b = blockIdx.x * 4 + (threadIdx.x >> 6);
    const int lane = threadIdx.x & 63;
    const u16* xp = o3 + (size_t)b * 2048;
    float xr[32];
    #pragma unroll
    for (int i = 0; i < 32; ++i) {
        int kk = lane + i * 64;
        int c = kk >> 4, h = (kk >> 2) & 3, w = kk & 3;
        xr[i] = bu2f(xp[h * 512 + w * 128 + c]);
    }
    float lg[10];
    #pragma unroll
    for (int o = 0; o < 10; ++o) {
        const float* wr = fw + (size_t)o * 2048;
        float s = 0.f;
        #pragma unroll
        for (int i = 0; i < 32; ++i) s += xr[i] * wr[lane + i * 64];
        #pragma unroll
        for (int d = 32; d > 0; d >>= 1) s += __shfl_xor(s, d);
        lg[o] = s + fb[o];
    }
    float m = lg[0];
    #pragma unroll
    for (int o = 1; o < 10; ++o) m = fmaxf(m, lg[o]);
    float den = 0.f;
    #pragma unroll
    for (int o = 0; o < 10; ++o) den += expf(lg[o] - m);
    float lse = logf(den);
    if (lane < 10) {
        float v = lg[0];
        #pragma unroll
        for (int o = 1; o < 10; ++o) v = (lane == o) ? lg[o] : v;
        out[(size_t)b * 10 + lane] = v - m - lse;
    }
}

extern "C" void kernel_launch(void* const* d_in, const int* in_sizes, int n_in,
                              void* d_out, int out_size, void* d_ws, size_t ws_size,
                              hipStream_t stream)
{
    const float* x    = (const float*)d_in[0];
    const float* Wlin = (const float*)d_in[1];
    const float* c1w  = (const float*)d_in[2];
    const float* c1b  = (const float*)d_in[3];
    const float* c2w  = (const float*)d_in[4];
    const float* c2b  = (const float*)d_in[5];
    const float* c3w  = (const float*)d_in[6];
    const float* c3b  = (const float*)d_in[7];
    const float* fw   = (const float*)d_in[8];
    const float* fb   = (const float*)d_in[9];
    const int* stage  = (const int*)d_in[10];
    float* out = (float*)d_out;

    const int B = in_sizes[0] / 3072;      // 8192

    // ws layout (bytes):
    //   xf  [0, B*6144)            bf16, dead after conv1
    //   o1  [B*6144, B*22528)      bf16, dead after conv2
    //   o2  [B*22528, B*30720)     bf16
    //   w2p [0, 37888)             written after conv1 (xf dead)
    //   w3p [40960, 190464)        same region
    //   o3  [B*6144, B*6144+B*4096)  reuse o1 region
    char* ws = (char*)d_ws;
    u16* xf  = (u16*)ws;
    u16* o1  = (u16*)(ws + (size_t)B * 6144);
    u16* o2  = (u16*)(ws + (size_t)B * 22528);
    u16* o3  = o1;
    u16* w2p = (u16*)ws;
    u16* w3p = (u16*)(ws + 40960);

    k_stage2<<<B, 256, 0, stream>>>(x, Wlin, stage, xf);
    k_conv1 <<<B, 256, 0, stream>>>(xf, c1w, c1b, o1);
    k_repack<<<288, 256, 0, stream>>>(c2w, c3w, w2p, w3p);
    k_conv2m<<<B, 256, 0, stream>>>(o1, w2p, c2b, o2);
    k_conv3m<<<dim3(B / 4, 2), 256, 0, stream>>>(o2, w3p, c3b, o3);
    k_fc    <<<B / 4, 256, 0, stream>>>(o3, fw, fb, out);
}

// Round 3
// 494.787 us; speedup vs baseline: 10.0361x; 1.9087x over previous
//
#include <hip/hip_runtime.h>
#include <hip/hip_bf16.h>

typedef unsigned short u16;   // bf16 bits
typedef __attribute__((ext_vector_type(8))) short short8v;   // 8 bf16 (4 VGPRs)
typedef __attribute__((ext_vector_type(4))) float f32x4;
typedef union { short8v v; uint u[4]; } pack8;

__device__ __forceinline__ float bu2f(u16 u) {
    return __uint_as_float(((unsigned)u) << 16);
}
__device__ __forceinline__ u16 f2bu(float f) {   // RNE f32->bf16
    unsigned u = __float_as_uint(f);
    u += 0x7fffu + ((u >> 16) & 1u);
    return (u16)(u >> 16);
}
__device__ __forceinline__ uint pk2(float a, float b) {
    return (uint)f2bu(a) | ((uint)f2bu(b) << 16);
}

// ---------------------------------------------------------------------------
// K-repack: all weights -> MFMA-friendly bf16 layouts in ws.
//  w1p  [32][72]: k = kh*16 + kw*3 + c (zeros elsewhere)         conv1
//  s2wp [96][72]: rows 0-47 W_lin hi, 48-95 W_lin lo; k<48 valid stage2
//  w2p  [64][296]: k = tap*32 + ic                               conv2
//  w3p  [128][584]: k = tap*64 + ic                              conv3
// ---------------------------------------------------------------------------
__global__ __launch_bounds__(256) void k_repack(
    const float* __restrict__ Wlin, const float* __restrict__ c1w,
    const float* __restrict__ c2w, const float* __restrict__ c3w,
    u16* __restrict__ w1p, u16* __restrict__ s2wp,
    u16* __restrict__ w2p, u16* __restrict__ w3p)
{
    int i = blockIdx.x * 256 + threadIdx.x;
    if (i < 32 * 72) {
        int oc = i / 72, k = i - oc * 72;
        int kh = k >> 4, e = k & 15;
        u16 v = 0;
        if (kh < 3 && e < 9) {
            int kw = e / 3, c = e - kw * 3;
            v = f2bu(c1w[((oc * 3 + c) * 3 + kh) * 3 + kw]);
        }
        w1p[i] = v;
    }
    if (i < 96 * 72) {
        int r = i / 72, k = i - r * 72;
        u16 v = 0;
        if (k < 48) {
            int o = r % 48;
            float w = Wlin[o * 48 + k];
            u16 hi = f2bu(w);
            v = (r < 48) ? hi : f2bu(w - bu2f(hi));
        }
        s2wp[i] = v;
    }
    if (i < 64 * 288) {
        int oc = i / 288, r = i - oc * 288;
        int tap = r >> 5, ic = r & 31;
        w2p[oc * 296 + r] = f2bu(c2w[(oc * 32 + ic) * 9 + tap]);
    }
    if (i < 128 * 576) {
        int oc = i / 576, r = i - oc * 576;
        int tap = r >> 6, ic = r & 63;
        w3p[oc * 584 + r] = f2bu(c3w[(oc * 64 + ic) * 9 + tap]);
    }
}

// ---------------------------------------------------------------------------
// K-front: stage2 (MFMA, W split hi/lo) + conv1 (MFMA, im2col-free) fused.
// One WG = one image (4 waves). x f32 -> o1 (B,16,16,32) bf16 NHWC.
//
// LDS map (u16 elems):
//   imgE[3488]   padded bf16 image [34][34][3], zero halo
//   imgO[3488]   same shifted by one elem: imgO[j] = img[j+1]
//   xb  [64][72] stage2 A (blocks x K48 pad 64)
//   s2w [96][72] stage2 W hi/lo
//   w1l [32][72] conv1 W, k = kh*16 + kw*3 + c
// ---------------------------------------------------------------------------
#define IMG_E 0
#define IMG_O 3488
#define XB    6976
#define S2W   11584
#define W1L   18496
#define LDSZ  20800

__global__ __launch_bounds__(256) void k_front(
    const float* __restrict__ x, const u16* __restrict__ s2wp,
    const u16* __restrict__ w1p, const float* __restrict__ cb,
    const int* __restrict__ stage, u16* __restrict__ o1)
{
    __shared__ __align__(16) u16 lds[LDSZ];
    const int b = blockIdx.x, t = threadIdx.x;
    const int wv = t >> 6, lane = t & 63, lr = lane & 15, q = lane >> 4;

    // zero img (E+O contiguous at offset 0): 6976 u16 = 3488 u32
    uint* zi = (uint*)lds;
    for (int i = t; i < 3488; i += 256) zi[i] = 0u;
    // weights -> LDS
    for (int i = t; i < 864; i += 256)
        *(short8v*)(&lds[S2W + i * 8]) = *(const short8v*)(&s2wp[i * 8]);
    for (int i = t; i < 288; i += 256)
        *(short8v*)(&lds[W1L + i * 8]) = *(const short8v*)(&w1p[i * 8]);

    const int sv = stage[0];
    if (sv == 2) {
        // build xb: thread t -> block n = t>>2, row ir = t&3 (12 contiguous f32)
        {
            const int n = t >> 2, ir = t & 3;
            const float* xp = x + (size_t)b * 3072 + (((n >> 3) * 4 + ir) * 96 + (n & 7) * 12);
            const float4 va = ((const float4*)xp)[0];
            const float4 vb = ((const float4*)xp)[1];
            const float4 vc = ((const float4*)xp)[2];
            uint* dst = (uint*)&lds[XB + n * 72 + ir * 12];
            dst[0] = pk2(va.x, va.y); dst[1] = pk2(va.z, va.w);
            dst[2] = pk2(vb.x, vb.y); dst[3] = pk2(vb.z, vb.w);
            dst[4] = pk2(vc.x, vc.y); dst[5] = pk2(vc.z, vc.w);
            if (ir < 2) {                       // zero k = 48..63
                uint* z2 = (uint*)&lds[XB + n * 72 + 48 + ir * 8];
                z2[0] = 0u; z2[1] = 0u; z2[2] = 0u; z2[3] = 0u;
            }
        }
        __syncthreads();
        // stage2 MFMA: wave = M-frag (16 blocks); N=48 (3 frags); K=64 (2 steps) x {hi,lo}
        short8v a0 = *(const short8v*)&lds[XB + (wv * 16 + lr) * 72 + q * 8];
        short8v a1 = *(const short8v*)&lds[XB + (wv * 16 + lr) * 72 + 32 + q * 8];
        f32x4 y[3];
        #pragma unroll
        for (int nf = 0; nf < 3; ++nf) {
            y[nf] = (f32x4){0.f, 0.f, 0.f, 0.f};
            short8v bh0 = *(const short8v*)&lds[S2W + (nf * 16 + lr) * 72 + q * 8];
            short8v bh1 = *(const short8v*)&lds[S2W + (nf * 16 + lr) * 72 + 32 + q * 8];
            short8v bl0 = *(const short8v*)&lds[S2W + (48 + nf * 16 + lr) * 72 + q * 8];
            short8v bl1 = *(const short8v*)&lds[S2W + (48 + nf * 16 + lr) * 72 + 32 + q * 8];
            y[nf] = __builtin_amdgcn_mfma_f32_16x16x32_bf16(a0, bh0, y[nf], 0, 0, 0);
            y[nf] = __builtin_amdgcn_mfma_f32_16x16x32_bf16(a1, bh1, y[nf], 0, 0, 0);
            y[nf] = __builtin_amdgcn_mfma_f32_16x16x32_bf16(a0, bl0, y[nf], 0, 0, 0);
            y[nf] = __builtin_amdgcn_mfma_f32_16x16x32_bf16(a1, bl1, y[nf], 0, 0, 0);
        }
        __syncthreads();   // img zero-fill complete everywhere before scatter
        // scatter y -> padded img (E and O copies)
        #pragma unroll
        for (int nf = 0; nf < 3; ++nf)
            #pragma unroll
            for (int r = 0; r < 4; ++r) {
                int n2 = wv * 16 + q * 4 + r;
                int o  = nf * 16 + lr;
                int ir = o / 12, rm = o - ir * 12;
                int jc = rm / 3, c = rm - jc * 3;
                int hh = (n2 >> 3) * 4 + ir, ww = (n2 & 7) * 4 + jc;
                int e  = ((hh + 1) * 34 + (ww + 1)) * 3 + c;
                u16 val = f2bu(y[nf][r]);
                lds[IMG_E + e] = val;
                lds[IMG_O + e - 1] = val;
            }
    } else {
        __syncthreads();
        for (int e = t; e < 3072; e += 256) {
            int hh = e / 96, rm = e - hh * 96;
            int ww = rm / 3, c = rm - ww * 3;
            u16 val = f2bu(x[(size_t)b * 3072 + e]);
            int ii = ((hh + 1) * 34 + (ww + 1)) * 3 + c;
            lds[IMG_E + ii] = val;
            lds[IMG_O + ii - 1] = val;
        }
    }
    __syncthreads();

    // conv1 MFMA: wave handles 256 positions (rows wv*8..wv*8+7 of 32x32).
    // A-frag: lane (lr,q): 8 contiguous bf16 at patch elem a (E/O-aligned b32 reads).
    short8v wf[2][2];
    #pragma unroll
    for (int nf = 0; nf < 2; ++nf)
        #pragma unroll
        for (int ks = 0; ks < 2; ++ks)
            wf[nf][ks] = *(const short8v*)&lds[W1L + (nf * 16 + lr) * 72 + ks * 32 + q * 8];
    const float bias[2] = {cb[lr], cb[16 + lr]};
    u16* op = o1 + (size_t)b * 8192;

    #pragma unroll
    for (int mc = 0; mc < 4; ++mc) {
        f32x4 acc[4][2];
        #pragma unroll
        for (int mi = 0; mi < 4; ++mi)
            #pragma unroll
            for (int nf = 0; nf < 2; ++nf) acc[mi][nf] = (f32x4){0.f, 0.f, 0.f, 0.f};
        #pragma unroll
        for (int mi = 0; mi < 4; ++mi) {
            const int p = wv * 256 + (mc * 4 + mi) * 16 + lr;
            const int ph = p >> 5, pw = p & 31;
            #pragma unroll
            for (int ks = 0; ks < 2; ++ks) {
                const int r = ks ? 2 : (q >> 1);
                const int a = 3 * ((ph + r) * 34 + pw) + (q & 1) * 8;
                const uint* sp = (a & 1) ? (const uint*)&lds[IMG_O + a - 1]
                                         : (const uint*)&lds[IMG_E + a];
                pack8 pk;
                pk.u[0] = sp[0]; pk.u[1] = sp[1]; pk.u[2] = sp[2]; pk.u[3] = sp[3];
                acc[mi][0] = __builtin_amdgcn_mfma_f32_16x16x32_bf16(pk.v, wf[0][ks], acc[mi][0], 0, 0, 0);
                acc[mi][1] = __builtin_amdgcn_mfma_f32_16x16x32_bf16(pk.v, wf[1][ks], acc[mi][1], 0, 0, 0);
            }
        }
        // epilogue: relu+bias, pool (w-pair = reg pair, h-pair = frag mi vs mi+2)
        #pragma unroll
        for (int pr = 0; pr < 2; ++pr)
            #pragma unroll
            for (int nf = 0; nf < 2; ++nf) {
                const float bb = bias[nf];
                #pragma unroll
                for (int j = 0; j < 2; ++j) {
                    float v = fmaxf(acc[pr][nf][2 * j] + bb, 0.f);
                    v = fmaxf(v, fmaxf(acc[pr][nf][2 * j + 1] + bb, 0.f));
                    v = fmaxf(v, fmaxf(acc[pr + 2][nf][2 * j] + bb, 0.f));
                    v = fmaxf(v, fmaxf(acc[pr + 2][nf][2 * j + 1] + bb, 0.f));
                    const int hq = wv * 4 + mc, wq = pr * 8 + q * 2 + j;
                    op[(hq * 16 + wq) * 32 + nf * 16 + lr] = f2bu(v);
                }
            }
    }
}

// ---------------------------------------------------------------------------
// K3: conv2 32->64 + ReLU + maxpool2, MFMA implicit GEMM (unchanged).
// ---------------------------------------------------------------------------
__global__ __launch_bounds__(256) void k_conv2m(
    const u16* __restrict__ o1, const u16* __restrict__ w2p,
    const float* __restrict__ cb, u16* __restrict__ o2)
{
    __shared__ u16 inl[12960];   // ((h)*18+w)*40 + ic ; zero halo
    __shared__ u16 wl[18944];    // [oc][296]
    const int b = blockIdx.x, t = threadIdx.x;
    uint* z = (uint*)inl;
    for (int i = t; i < 6480; i += 256) z[i] = 0u;
    for (int i = t; i < 2368; i += 256)
        *(short8v*)(&wl[i * 8]) = *(const short8v*)(&w2p[i * 8]);
    __syncthreads();
    const u16* ip = o1 + (size_t)b * 8192;
    for (int e = t; e < 1024; e += 256) {
        int ic8 = e & 3, w = (e >> 2) & 15, h = e >> 6;
        *(short8v*)(&inl[((h + 1) * 18 + (w + 1)) * 40 + ic8 * 8]) =
            *(const short8v*)(&ip[e * 8]);
    }
    __syncthreads();
    const int wv = t >> 6, lane = t & 63;
    const int lr = lane & 15, q = lane >> 4;
    f32x4 acc[4][4];
    #pragma unroll
    for (int m = 0; m < 4; ++m)
        #pragma unroll
        for (int n = 0; n < 4; ++n) acc[m][n] = (f32x4){0.f, 0.f, 0.f, 0.f};
    #pragma unroll
    for (int kh = 0; kh < 3; ++kh)
        #pragma unroll
        for (int kw = 0; kw < 3; ++kw) {
            short8v af[4], bf[4];
            #pragma unroll
            for (int m = 0; m < 4; ++m)
                af[m] = *(const short8v*)(&inl[((wv * 4 + m + kh) * 18 + lr + kw) * 40 + q * 8]);
            #pragma unroll
            for (int n = 0; n < 4; ++n)
                bf[n] = *(const short8v*)(&wl[(n * 16 + lr) * 296 + (kh * 3 + kw) * 32 + q * 8]);
            #pragma unroll
            for (int m = 0; m < 4; ++m)
                #pragma unroll
                for (int n = 0; n < 4; ++n)
                    acc[m][n] = __builtin_amdgcn_mfma_f32_16x16x32_bf16(af[m], bf[n], acc[m][n], 0, 0, 0);
        }
    u16* op = o2 + (size_t)b * 4096;
    #pragma unroll
    for (int n = 0; n < 4; ++n) {
        float bias = cb[n * 16 + lr];
        #pragma unroll
        for (int mp = 0; mp < 2; ++mp) {
            #pragma unroll
            for (int p = 0; p < 2; ++p) {
                float v = fmaxf(acc[2 * mp][n][2 * p] + bias, 0.f);
                v = fmaxf(v, fmaxf(acc[2 * mp][n][2 * p + 1] + bias, 0.f));
                v = fmaxf(v, fmaxf(acc[2 * mp + 1][n][2 * p] + bias, 0.f));
                v = fmaxf(v, fmaxf(acc[2 * mp + 1][n][2 * p + 1] + bias, 0.f));
                int hq = wv * 2 + mp, wq = 2 * q + p;
                op[(hq * 8 + wq) * 64 + n * 16 + lr] = f2bu(v);
            }
        }
    }
}

// ---------------------------------------------------------------------------
// K4: conv3 64->128 + ReLU + maxpool2, MFMA implicit GEMM (unchanged).
// ---------------------------------------------------------------------------
__global__ __launch_bounds__(256) void k_conv3m(
    const u16* __restrict__ o2, const u16* __restrict__ w3p,
    const float* __restrict__ cb, u16* __restrict__ o3)
{
    __shared__ u16 inl[28800];   // (u*100 + h*10 + w)*72 + ic ; zero halo
    __shared__ u16 wl[37376];    // [ocl][584]
    const int b0 = blockIdx.x * 4, ocb = blockIdx.y * 64, t = threadIdx.x;
    uint* z = (uint*)inl;
    for (int i = t; i < 14400; i += 256) z[i] = 0u;
    const u16* wp = w3p + (size_t)ocb * 584;
    for (int i = t; i < 4672; i += 256)
        *(short8v*)(&wl[i * 8]) = *(const short8v*)(&wp[i * 8]);
    __syncthreads();
    for (int e = t; e < 2048; e += 256) {
        int u = e >> 9, rem = e & 511;
        int ic8 = rem & 7, w = (rem >> 3) & 7, h = rem >> 6;
        *(short8v*)(&inl[(u * 100 + (h + 1) * 10 + (w + 1)) * 72 + ic8 * 8]) =
            *(const short8v*)(&o2[(size_t)(b0 + u) * 4096 + rem * 8]);
    }
    __syncthreads();
    const int wv = t >> 6, lane = t & 63;
    const int lr = lane & 15, q = lane >> 4;
    const int hA = lr >> 3, wA = lr & 7;
    f32x4 acc[4][4];
    #pragma unroll
    for (int m = 0; m < 4; ++m)
        #pragma unroll
        for (int n = 0; n < 4; ++n) acc[m][n] = (f32x4){0.f, 0.f, 0.f, 0.f};
    #pragma unroll
    for (int tap = 0; tap < 9; ++tap) {
        const int kh = tap / 3, kw = tap - kh * 3;
        #pragma unroll
        for (int half = 0; half < 2; ++half) {
            short8v af[4], bf[4];
            #pragma unroll
            for (int m = 0; m < 4; ++m)
                af[m] = *(const short8v*)(&inl[(wv * 100 + (m * 2 + hA + kh) * 10 + wA + kw) * 72
                                               + half * 32 + q * 8]);
            #pragma unroll
            for (int n = 0; n < 4; ++n)
                bf[n] = *(const short8v*)(&wl[(n * 16 + lr) * 584 + tap * 64 + half * 32 + q * 8]);
            #pragma unroll
            for (int m = 0; m < 4; ++m)
                #pragma unroll
                for (int n = 0; n < 4; ++n)
                    acc[m][n] = __builtin_amdgcn_mfma_f32_16x16x32_bf16(af[m], bf[n], acc[m][n], 0, 0, 0);
        }
    }
    #pragma unroll
    for (int n = 0; n < 4; ++n) {
        float bias = cb[ocb + n * 16 + lr];
        #pragma unroll
        for (int m = 0; m < 4; ++m) {
            #pragma unroll
            for (int p = 0; p < 2; ++p) {
                float v = fmaxf(acc[m][n][2 * p] + bias, 0.f);
                v = fmaxf(v, fmaxf(acc[m][n][2 * p + 1] + bias, 0.f));
                float v2 = fmaxf(v, __shfl_xor(v, 32));
                if (lane < 32) {
                    int wq = (q & 1) * 2 + p;
                    o3[(size_t)(b0 + wv) * 2048 + (m * 4 + wq) * 128 + ocb + n * 16 + lr] = f2bu(v2);
                }
            }
        }
    }
}

// ---------------------------------------------------------------------------
// K5: fc (2048->10, NCHW flatten) + log_softmax. One wave/image.
// ---------------------------------------------------------------------------
__global__ __launch_bounds__(256) void k_fc(
    const u16* __restrict__ o3, const float* __restrict__ fw,
    const float* __restrict__ fb, float* __restrict__ out)
{
    const int b = blockIdx.x * 4 + (threadIdx.x >> 6);
    const int lane = threadIdx.x & 63;
    const u16* xp = o3 + (size_t)b * 2048;
    float xr[32];
    #pragma unroll
    for (int i = 0; i < 32; ++i) {
        int kk = lane + i * 64;
        int c = kk >> 4, h = (kk >> 2) & 3, w = kk & 3;
        xr[i] = bu2f(xp[h * 512 + w * 128 + c]);
    }
    float lg[10];
    #pragma unroll
    for (int o = 0; o < 10; ++o) {
        const float* wr = fw + (size_t)o * 2048;
        float s = 0.f;
        #pragma unroll
        for (int i = 0; i < 32; ++i) s += xr[i] * wr[lane + i * 64];
        #pragma unroll
        for (int d = 32; d > 0; d >>= 1) s += __shfl_xor(s, d);
        lg[o] = s + fb[o];
    }
    float m = lg[0];
    #pragma unroll
    for (int o = 1; o < 10; ++o) m = fmaxf(m, lg[o]);
    float den = 0.f;
    #pragma unroll
    for (int o = 0; o < 10; ++o) den += expf(lg[o] - m);
    float lse = logf(den);
    if (lane < 10) {
        float v = lg[0];
        #pragma unroll
        for (int o = 1; o < 10; ++o) v = (lane == o) ? lg[o] : v;
        out[(size_t)b * 10 + lane] = v - m - lse;
    }
}

extern "C" void kernel_launch(void* const* d_in, const int* in_sizes, int n_in,
                              void* d_out, int out_size, void* d_ws, size_t ws_size,
                              hipStream_t stream)
{
    const float* x    = (const float*)d_in[0];
    const float* Wlin = (const float*)d_in[1];
    const float* c1w  = (const float*)d_in[2];
    const float* c1b  = (const float*)d_in[3];
    const float* c2w  = (const float*)d_in[4];
    const float* c2b  = (const float*)d_in[5];
    const float* c3w  = (const float*)d_in[6];
    const float* c3b  = (const float*)d_in[7];
    const float* fw   = (const float*)d_in[8];
    const float* fb   = (const float*)d_in[9];
    const int* stage  = (const int*)d_in[10];
    float* out = (float*)d_out;

    const int B = in_sizes[0] / 3072;      // 8192

    // ws layout (bytes):
    //   o1  [0, B*16384)
    //   o2  [B*16384, B*24576)
    //   o3  [B*24576, B*28672)
    //   weights at WB = B*28672:
    //     w1p  +0      (4608)
    //     s2wp +4608   (13824)
    //     w2p  +18432  (37888)
    //     w3p  +56320  (149504)
    char* ws = (char*)d_ws;
    u16* o1   = (u16*)ws;
    u16* o2   = (u16*)(ws + (size_t)B * 16384);
    u16* o3   = (u16*)(ws + (size_t)B * 24576);
    char* WB  = ws + (size_t)B * 28672;
    u16* w1p  = (u16*)(WB);
    u16* s2wp = (u16*)(WB + 4608);
    u16* w2p  = (u16*)(WB + 18432);
    u16* w3p  = (u16*)(WB + 56320);

    k_repack<<<288, 256, 0, stream>>>(Wlin, c1w, c2w, c3w, w1p, s2wp, w2p, w3p);
    k_front <<<B, 256, 0, stream>>>(x, s2wp, w1p, c1b, stage, o1);
    k_conv2m<<<B, 256, 0, stream>>>(o1, w2p, c2b, o2);
    k_conv3m<<<dim3(B / 4, 2), 256, 0, stream>>>(o2, w3p, c3b, o3);
    k_fc    <<<B / 4, 256, 0, stream>>>(o3, fw, fb, out);
}

// Round 4
// 416.951 us; speedup vs baseline: 11.9096x; 1.1867x over previous
//
#include <hip/hip_runtime.h>
#include <hip/hip_bf16.h>

typedef unsigned short u16;   // bf16 bits
typedef __attribute__((ext_vector_type(8))) short short8v;   // 8 bf16 (4 VGPRs)
typedef __attribute__((ext_vector_type(4))) float f32x4;
typedef union { short8v v; uint u[4]; } pack8;

__device__ __forceinline__ float bu2f(u16 u) {
    return __uint_as_float(((unsigned)u) << 16);
}
__device__ __forceinline__ u16 f2bu(float f) {   // RNE f32->bf16
    unsigned u = __float_as_uint(f);
    u += 0x7fffu + ((u >> 16) & 1u);
    return (u16)(u >> 16);
}
__device__ __forceinline__ uint pk2(float a, float b) {
    return (uint)f2bu(a) | ((uint)f2bu(b) << 16);
}

// ---------------------------------------------------------------------------
// K-repack: all weights -> MFMA-friendly bf16 layouts in ws.
//  w1p  [32][72]: k = kh*16 + kw*3 + c (zeros elsewhere)         conv1
//  s2wp [96][72]: rows 0-47 W_lin hi, 48-95 W_lin lo; k<48 valid stage2
//  w2p  [64][296]: k = tap*32 + ic                               conv2
//  w3p  [128][584]: k = tap*64 + ic                              conv3
// ---------------------------------------------------------------------------
__global__ __launch_bounds__(256) void k_repack(
    const float* __restrict__ Wlin, const float* __restrict__ c1w,
    const float* __restrict__ c2w, const float* __restrict__ c3w,
    u16* __restrict__ w1p, u16* __restrict__ s2wp,
    u16* __restrict__ w2p, u16* __restrict__ w3p)
{
    int i = blockIdx.x * 256 + threadIdx.x;
    if (i < 32 * 72) {
        int oc = i / 72, k = i - oc * 72;
        int kh = k >> 4, e = k & 15;
        u16 v = 0;
        if (kh < 3 && e < 9) {
            int kw = e / 3, c = e - kw * 3;
            v = f2bu(c1w[((oc * 3 + c) * 3 + kh) * 3 + kw]);
        }
        w1p[i] = v;
    }
    if (i < 96 * 72) {
        int r = i / 72, k = i - r * 72;
        u16 v = 0;
        if (k < 48) {
            int o = r % 48;
            float w = Wlin[o * 48 + k];
            u16 hi = f2bu(w);
            v = (r < 48) ? hi : f2bu(w - bu2f(hi));
        }
        s2wp[i] = v;
    }
    if (i < 64 * 288) {
        int oc = i / 288, r = i - oc * 288;
        int tap = r >> 5, ic = r & 31;
        w2p[oc * 296 + r] = f2bu(c2w[(oc * 32 + ic) * 9 + tap]);
    }
    if (i < 128 * 576) {
        int oc = i / 576, r = i - oc * 576;
        int tap = r >> 6, ic = r & 63;
        w3p[oc * 584 + r] = f2bu(c3w[(oc * 64 + ic) * 9 + tap]);
    }
}

// ---------------------------------------------------------------------------
// K-front: stage2 (MFMA, W split hi/lo) + conv1 (MFMA, im2col-free) fused.
// ---------------------------------------------------------------------------
#define IMG_E 0
#define IMG_O 3488
#define XB    6976
#define S2W   11584
#define W1L   18496
#define LDSZ  20800

__global__ __launch_bounds__(256) void k_front(
    const float* __restrict__ x, const u16* __restrict__ s2wp,
    const u16* __restrict__ w1p, const float* __restrict__ cb,
    const int* __restrict__ stage, u16* __restrict__ o1)
{
    __shared__ __align__(16) u16 lds[LDSZ];
    const int b = blockIdx.x, t = threadIdx.x;
    const int wv = t >> 6, lane = t & 63, lr = lane & 15, q = lane >> 4;

    uint* zi = (uint*)lds;
    for (int i = t; i < 3488; i += 256) zi[i] = 0u;
    for (int i = t; i < 864; i += 256)
        *(short8v*)(&lds[S2W + i * 8]) = *(const short8v*)(&s2wp[i * 8]);
    for (int i = t; i < 288; i += 256)
        *(short8v*)(&lds[W1L + i * 8]) = *(const short8v*)(&w1p[i * 8]);

    const int sv = stage[0];
    if (sv == 2) {
        {
            const int n = t >> 2, ir = t & 3;
            const float* xp = x + (size_t)b * 3072 + (((n >> 3) * 4 + ir) * 96 + (n & 7) * 12);
            const float4 va = ((const float4*)xp)[0];
            const float4 vb = ((const float4*)xp)[1];
            const float4 vc = ((const float4*)xp)[2];
            uint* dst = (uint*)&lds[XB + n * 72 + ir * 12];
            dst[0] = pk2(va.x, va.y); dst[1] = pk2(va.z, va.w);
            dst[2] = pk2(vb.x, vb.y); dst[3] = pk2(vb.z, vb.w);
            dst[4] = pk2(vc.x, vc.y); dst[5] = pk2(vc.z, vc.w);
            if (ir < 2) {
                uint* z2 = (uint*)&lds[XB + n * 72 + 48 + ir * 8];
                z2[0] = 0u; z2[1] = 0u; z2[2] = 0u; z2[3] = 0u;
            }
        }
        __syncthreads();
        short8v a0 = *(const short8v*)&lds[XB + (wv * 16 + lr) * 72 + q * 8];
        short8v a1 = *(const short8v*)&lds[XB + (wv * 16 + lr) * 72 + 32 + q * 8];
        f32x4 y[3];
        #pragma unroll
        for (int nf = 0; nf < 3; ++nf) {
            y[nf] = (f32x4){0.f, 0.f, 0.f, 0.f};
            short8v bh0 = *(const short8v*)&lds[S2W + (nf * 16 + lr) * 72 + q * 8];
            short8v bh1 = *(const short8v*)&lds[S2W + (nf * 16 + lr) * 72 + 32 + q * 8];
            short8v bl0 = *(const short8v*)&lds[S2W + (48 + nf * 16 + lr) * 72 + q * 8];
            short8v bl1 = *(const short8v*)&lds[S2W + (48 + nf * 16 + lr) * 72 + 32 + q * 8];
            y[nf] = __builtin_amdgcn_mfma_f32_16x16x32_bf16(a0, bh0, y[nf], 0, 0, 0);
            y[nf] = __builtin_amdgcn_mfma_f32_16x16x32_bf16(a1, bh1, y[nf], 0, 0, 0);
            y[nf] = __builtin_amdgcn_mfma_f32_16x16x32_bf16(a0, bl0, y[nf], 0, 0, 0);
            y[nf] = __builtin_amdgcn_mfma_f32_16x16x32_bf16(a1, bl1, y[nf], 0, 0, 0);
        }
        __syncthreads();
        #pragma unroll
        for (int nf = 0; nf < 3; ++nf)
            #pragma unroll
            for (int r = 0; r < 4; ++r) {
                int n2 = wv * 16 + q * 4 + r;
                int o  = nf * 16 + lr;
                int ir = o / 12, rm = o - ir * 12;
                int jc = rm / 3, c = rm - jc * 3;
                int hh = (n2 >> 3) * 4 + ir, ww = (n2 & 7) * 4 + jc;
                int e  = ((hh + 1) * 34 + (ww + 1)) * 3 + c;
                u16 val = f2bu(y[nf][r]);
                lds[IMG_E + e] = val;
                lds[IMG_O + e - 1] = val;
            }
    } else {
        __syncthreads();
        for (int e = t; e < 3072; e += 256) {
            int hh = e / 96, rm = e - hh * 96;
            int ww = rm / 3, c = rm - ww * 3;
            u16 val = f2bu(x[(size_t)b * 3072 + e]);
            int ii = ((hh + 1) * 34 + (ww + 1)) * 3 + c;
            lds[IMG_E + ii] = val;
            lds[IMG_O + ii - 1] = val;
        }
    }
    __syncthreads();

    short8v wf[2][2];
    #pragma unroll
    for (int nf = 0; nf < 2; ++nf)
        #pragma unroll
        for (int ks = 0; ks < 2; ++ks)
            wf[nf][ks] = *(const short8v*)&lds[W1L + (nf * 16 + lr) * 72 + ks * 32 + q * 8];
    const float bias[2] = {cb[lr], cb[16 + lr]};
    u16* op = o1 + (size_t)b * 8192;

    #pragma unroll
    for (int mc = 0; mc < 4; ++mc) {
        f32x4 acc[4][2];
        #pragma unroll
        for (int mi = 0; mi < 4; ++mi)
            #pragma unroll
            for (int nf = 0; nf < 2; ++nf) acc[mi][nf] = (f32x4){0.f, 0.f, 0.f, 0.f};
        #pragma unroll
        for (int mi = 0; mi < 4; ++mi) {
            const int p = wv * 256 + (mc * 4 + mi) * 16 + lr;
            const int ph = p >> 5, pw = p & 31;
            #pragma unroll
            for (int ks = 0; ks < 2; ++ks) {
                const int r = ks ? 2 : (q >> 1);
                const int a = 3 * ((ph + r) * 34 + pw) + (q & 1) * 8;
                const uint* sp = (a & 1) ? (const uint*)&lds[IMG_O + a - 1]
                                         : (const uint*)&lds[IMG_E + a];
                pack8 pk;
                pk.u[0] = sp[0]; pk.u[1] = sp[1]; pk.u[2] = sp[2]; pk.u[3] = sp[3];
                acc[mi][0] = __builtin_amdgcn_mfma_f32_16x16x32_bf16(pk.v, wf[0][ks], acc[mi][0], 0, 0, 0);
                acc[mi][1] = __builtin_amdgcn_mfma_f32_16x16x32_bf16(pk.v, wf[1][ks], acc[mi][1], 0, 0, 0);
            }
        }
        #pragma unroll
        for (int pr = 0; pr < 2; ++pr)
            #pragma unroll
            for (int nf = 0; nf < 2; ++nf) {
                const float bb = bias[nf];
                #pragma unroll
                for (int j = 0; j < 2; ++j) {
                    float v = fmaxf(acc[pr][nf][2 * j] + bb, 0.f);
                    v = fmaxf(v, fmaxf(acc[pr][nf][2 * j + 1] + bb, 0.f));
                    v = fmaxf(v, fmaxf(acc[pr + 2][nf][2 * j] + bb, 0.f));
                    v = fmaxf(v, fmaxf(acc[pr + 2][nf][2 * j + 1] + bb, 0.f));
                    const int hq = wv * 4 + mc, wq = pr * 8 + q * 2 + j;
                    op[(hq * 16 + wq) * 32 + nf * 16 + lr] = f2bu(v);
                }
            }
    }
}

// ---------------------------------------------------------------------------
// K3: conv2 32->64 + ReLU + maxpool2, MFMA implicit GEMM (unchanged).
// ---------------------------------------------------------------------------
__global__ __launch_bounds__(256) void k_conv2m(
    const u16* __restrict__ o1, const u16* __restrict__ w2p,
    const float* __restrict__ cb, u16* __restrict__ o2)
{
    __shared__ u16 inl[12960];   // ((h)*18+w)*40 + ic ; zero halo
    __shared__ u16 wl[18944];    // [oc][296]
    const int b = blockIdx.x, t = threadIdx.x;
    uint* z = (uint*)inl;
    for (int i = t; i < 6480; i += 256) z[i] = 0u;
    for (int i = t; i < 2368; i += 256)
        *(short8v*)(&wl[i * 8]) = *(const short8v*)(&w2p[i * 8]);
    __syncthreads();
    const u16* ip = o1 + (size_t)b * 8192;
    for (int e = t; e < 1024; e += 256) {
        int ic8 = e & 3, w = (e >> 2) & 15, h = e >> 6;
        *(short8v*)(&inl[((h + 1) * 18 + (w + 1)) * 40 + ic8 * 8]) =
            *(const short8v*)(&ip[e * 8]);
    }
    __syncthreads();
    const int wv = t >> 6, lane = t & 63;
    const int lr = lane & 15, q = lane >> 4;
    f32x4 acc[4][4];
    #pragma unroll
    for (int m = 0; m < 4; ++m)
        #pragma unroll
        for (int n = 0; n < 4; ++n) acc[m][n] = (f32x4){0.f, 0.f, 0.f, 0.f};
    #pragma unroll
    for (int kh = 0; kh < 3; ++kh)
        #pragma unroll
        for (int kw = 0; kw < 3; ++kw) {
            short8v af[4], bf[4];
            #pragma unroll
            for (int m = 0; m < 4; ++m)
                af[m] = *(const short8v*)(&inl[((wv * 4 + m + kh) * 18 + lr + kw) * 40 + q * 8]);
            #pragma unroll
            for (int n = 0; n < 4; ++n)
                bf[n] = *(const short8v*)(&wl[(n * 16 + lr) * 296 + (kh * 3 + kw) * 32 + q * 8]);
            #pragma unroll
            for (int m = 0; m < 4; ++m)
                #pragma unroll
                for (int n = 0; n < 4; ++n)
                    acc[m][n] = __builtin_amdgcn_mfma_f32_16x16x32_bf16(af[m], bf[n], acc[m][n], 0, 0, 0);
        }
    u16* op = o2 + (size_t)b * 4096;
    #pragma unroll
    for (int n = 0; n < 4; ++n) {
        float bias = cb[n * 16 + lr];
        #pragma unroll
        for (int mp = 0; mp < 2; ++mp) {
            #pragma unroll
            for (int p = 0; p < 2; ++p) {
                float v = fmaxf(acc[2 * mp][n][2 * p] + bias, 0.f);
                v = fmaxf(v, fmaxf(acc[2 * mp][n][2 * p + 1] + bias, 0.f));
                v = fmaxf(v, fmaxf(acc[2 * mp + 1][n][2 * p] + bias, 0.f));
                v = fmaxf(v, fmaxf(acc[2 * mp + 1][n][2 * p + 1] + bias, 0.f));
                int hq = wv * 2 + mp, wq = 2 * q + p;
                op[(hq * 8 + wq) * 64 + n * 16 + lr] = f2bu(v);
            }
        }
    }
}

// ---------------------------------------------------------------------------
// K4: conv3 64->128 + ReLU + maxpool2, MFMA implicit GEMM.
// v2: weights read directly from global (L2-hot), depth-2 pipelined; LDS holds
// only the input tile (57.6 KB) -> 2 blocks/CU instead of 1.
// ---------------------------------------------------------------------------
__global__ __launch_bounds__(256) void k_conv3m(
    const u16* __restrict__ o2, const u16* __restrict__ w3p,
    const float* __restrict__ cb, u16* __restrict__ o3)
{
    __shared__ u16 inl[28800];   // (u*100 + h*10 + w)*72 + ic ; zero halo
    const int b0 = blockIdx.x * 4, ocb = blockIdx.y * 64, t = threadIdx.x;
    uint* z = (uint*)inl;
    for (int i = t; i < 14400; i += 256) z[i] = 0u;
    __syncthreads();
    for (int e = t; e < 2048; e += 256) {
        int u = e >> 9, rem = e & 511;
        int ic8 = rem & 7, w = (rem >> 3) & 7, h = rem >> 6;
        *(short8v*)(&inl[(u * 100 + (h + 1) * 10 + (w + 1)) * 72 + ic8 * 8]) =
            *(const short8v*)(&o2[(size_t)(b0 + u) * 4096 + rem * 8]);
    }
    __syncthreads();
    const int wv = t >> 6, lane = t & 63;
    const int lr = lane & 15, q = lane >> 4;
    const int hA = lr >> 3, wA = lr & 7;
    // per-lane weight base: row = ocb + lr (n adds 16 rows), col = q*8 (+64/tap +32/half)
    const u16* wb = w3p + ((size_t)(ocb + lr)) * 584 + q * 8;

    f32x4 acc[4][4];
    #pragma unroll
    for (int m = 0; m < 4; ++m)
        #pragma unroll
        for (int n = 0; n < 4; ++n) acc[m][n] = (f32x4){0.f, 0.f, 0.f, 0.f};

    // B-frag pipeline, depth 2, rotating triple buffer (statically indexed).
    short8v bfr[3][4];
    #pragma unroll
    for (int n = 0; n < 4; ++n) {
        bfr[0][n] = *(const short8v*)(wb + n * (16 * 584) + 0);
        bfr[1][n] = *(const short8v*)(wb + n * (16 * 584) + 32);
    }
    #pragma unroll
    for (int s = 0; s < 18; ++s) {
        if (s + 2 < 18) {
            const int off2 = ((s + 2) >> 1) * 64 + ((s + 2) & 1) * 32;
            #pragma unroll
            for (int n = 0; n < 4; ++n)
                bfr[(s + 2) % 3][n] = *(const short8v*)(wb + n * (16 * 584) + off2);
        }
        const int tap = s >> 1, half = s & 1;
        const int kh = tap / 3, kw = tap - kh * 3;
        short8v af[4];
        #pragma unroll
        for (int m = 0; m < 4; ++m)
            af[m] = *(const short8v*)(&inl[(wv * 100 + (m * 2 + hA + kh) * 10 + wA + kw) * 72
                                           + half * 32 + q * 8]);
        #pragma unroll
        for (int m = 0; m < 4; ++m)
            #pragma unroll
            for (int n = 0; n < 4; ++n)
                acc[m][n] = __builtin_amdgcn_mfma_f32_16x16x32_bf16(af[m], bfr[s % 3][n], acc[m][n], 0, 0, 0);
    }
    #pragma unroll
    for (int n = 0; n < 4; ++n) {
        float bias = cb[ocb + n * 16 + lr];
        #pragma unroll
        for (int m = 0; m < 4; ++m) {
            #pragma unroll
            for (int p = 0; p < 2; ++p) {
                float v = fmaxf(acc[m][n][2 * p] + bias, 0.f);
                v = fmaxf(v, fmaxf(acc[m][n][2 * p + 1] + bias, 0.f));
                float v2 = fmaxf(v, __shfl_xor(v, 32));
                if (lane < 32) {
                    int wq = (q & 1) * 2 + p;
                    o3[(size_t)(b0 + wv) * 2048 + (m * 4 + wq) * 128 + ocb + n * 16 + lr] = f2bu(v2);
                }
            }
        }
    }
}

// ---------------------------------------------------------------------------
// K5: fc (2048->10, NCHW flatten) + log_softmax. One wave/image.
// ---------------------------------------------------------------------------
__global__ __launch_bounds__(256) void k_fc(
    const u16* __restrict__ o3, const float* __restrict__ fw,
    const float* __restrict__ fb, float* __restrict__ out)
{
    const int b = blockIdx.x * 4 + (threadIdx.x >> 6);
    const int lane = threadIdx.x & 63;
    const u16* xp = o3 + (size_t)b * 2048;
    float xr[32];
    #pragma unroll
    for (int i = 0; i < 32; ++i) {
        int kk = lane + i * 64;
        int c = kk >> 4, h = (kk >> 2) & 3, w = kk & 3;
        xr[i] = bu2f(xp[h * 512 + w * 128 + c]);
    }
    float lg[10];
    #pragma unroll
    for (int o = 0; o < 10; ++o) {
        const float* wr = fw + (size_t)o * 2048;
        float s = 0.f;
        #pragma unroll
        for (int i = 0; i < 32; ++i) s += xr[i] * wr[lane + i * 64];
        #pragma unroll
        for (int d = 32; d > 0; d >>= 1) s += __shfl_xor(s, d);
        lg[o] = s + fb[o];
    }
    float m = lg[0];
    #pragma unroll
    for (int o = 1; o < 10; ++o) m = fmaxf(m, lg[o]);
    float den = 0.f;
    #pragma unroll
    for (int o = 0; o < 10; ++o) den += expf(lg[o] - m);
    float lse = logf(den);
    if (lane < 10) {
        float v = lg[0];
        #pragma unroll
        for (int o = 1; o < 10; ++o) v = (lane == o) ? lg[o] : v;
        out[(size_t)b * 10 + lane] = v - m - lse;
    }
}

extern "C" void kernel_launch(void* const* d_in, const int* in_sizes, int n_in,
                              void* d_out, int out_size, void* d_ws, size_t ws_size,
                              hipStream_t stream)
{
    const float* x    = (const float*)d_in[0];
    const float* Wlin = (const float*)d_in[1];
    const float* c1w  = (const float*)d_in[2];
    const float* c1b  = (const float*)d_in[3];
    const float* c2w  = (const float*)d_in[4];
    const float* c2b  = (const float*)d_in[5];
    const float* c3w  = (const float*)d_in[6];
    const float* c3b  = (const float*)d_in[7];
    const float* fw   = (const float*)d_in[8];
    const float* fb   = (const float*)d_in[9];
    const int* stage  = (const int*)d_in[10];
    float* out = (float*)d_out;

    const int B = in_sizes[0] / 3072;      // 8192

    char* ws = (char*)d_ws;
    u16* o1   = (u16*)ws;
    u16* o2   = (u16*)(ws + (size_t)B * 16384);
    u16* o3   = (u16*)(ws + (size_t)B * 24576);
    char* WB  = ws + (size_t)B * 28672;
    u16* w1p  = (u16*)(WB);
    u16* s2wp = (u16*)(WB + 4608);
    u16* w2p  = (u16*)(WB + 18432);
    u16* w3p  = (u16*)(WB + 56320);

    k_repack<<<288, 256, 0, stream>>>(Wlin, c1w, c2w, c3w, w1p, s2wp, w2p, w3p);
    k_front <<<B, 256, 0, stream>>>(x, s2wp, w1p, c1b, stage, o1);
    k_conv2m<<<B, 256, 0, stream>>>(o1, w2p, c2b, o2);
    k_conv3m<<<dim3(B / 4, 2), 256, 0, stream>>>(o2, w3p, c3b, o3);
    k_fc    <<<B / 4, 256, 0, stream>>>(o3, fw, fb, out);
}

// Round 5
// 369.968 us; speedup vs baseline: 13.4221x; 1.1270x over previous
//
#include <hip/hip_runtime.h>
#include <hip/hip_bf16.h>

typedef unsigned short u16;   // bf16 bits
typedef __attribute__((ext_vector_type(8))) short short8v;   // 8 bf16 (4 VGPRs)
typedef __attribute__((ext_vector_type(4))) float f32x4;
typedef union { short8v v; uint u[4]; } pack8;

__device__ __forceinline__ float bu2f(u16 u) {
    return __uint_as_float(((unsigned)u) << 16);
}
__device__ __forceinline__ u16 f2bu(float f) {   // RNE f32->bf16
    unsigned u = __float_as_uint(f);
    u += 0x7fffu + ((u >> 16) & 1u);
    return (u16)(u >> 16);
}
__device__ __forceinline__ uint pk2(float a, float b) {
    return (uint)f2bu(a) | ((uint)f2bu(b) << 16);
}

// ---------------------------------------------------------------------------
// K-repack: all weights -> MFMA-friendly bf16 layouts in ws.
//  w1p  [32][72]: k = kh*16 + kw*3 + c (zeros elsewhere)         conv1
//  s2wp [96][72]: rows 0-47 W_lin hi, 48-95 W_lin lo; k<48 valid stage2
//  w2p  [64][296]: k = tap*32 + ic                               conv2
//  w3p  [128][584]: k = tap*64 + ic                              conv3
// ---------------------------------------------------------------------------
__global__ __launch_bounds__(256) void k_repack(
    const float* __restrict__ Wlin, const float* __restrict__ c1w,
    const float* __restrict__ c2w, const float* __restrict__ c3w,
    u16* __restrict__ w1p, u16* __restrict__ s2wp,
    u16* __restrict__ w2p, u16* __restrict__ w3p)
{
    int i = blockIdx.x * 256 + threadIdx.x;
    if (i < 32 * 72) {
        int oc = i / 72, k = i - oc * 72;
        int kh = k >> 4, e = k & 15;
        u16 v = 0;
        if (kh < 3 && e < 9) {
            int kw = e / 3, c = e - kw * 3;
            v = f2bu(c1w[((oc * 3 + c) * 3 + kh) * 3 + kw]);
        }
        w1p[i] = v;
    }
    if (i < 96 * 72) {
        int r = i / 72, k = i - r * 72;
        u16 v = 0;
        if (k < 48) {
            int o = r % 48;
            float w = Wlin[o * 48 + k];
            u16 hi = f2bu(w);
            v = (r < 48) ? hi : f2bu(w - bu2f(hi));
        }
        s2wp[i] = v;
    }
    if (i < 64 * 288) {
        int oc = i / 288, r = i - oc * 288;
        int tap = r >> 5, ic = r & 31;
        w2p[oc * 296 + r] = f2bu(c2w[(oc * 32 + ic) * 9 + tap]);
    }
    if (i < 128 * 576) {
        int oc = i / 576, r = i - oc * 576;
        int tap = r >> 6, ic = r & 63;
        w3p[oc * 584 + r] = f2bu(c3w[(oc * 64 + ic) * 9 + tap]);
    }
}

// ---------------------------------------------------------------------------
// K-front: stage2 (MFMA, W split hi/lo) + conv1 (MFMA, im2col-free) fused.
// ---------------------------------------------------------------------------
#define IMG_E 0
#define IMG_O 3488
#define XB    6976
#define S2W   11584
#define W1L   18496
#define LDSZ  20800

__global__ __launch_bounds__(256) void k_front(
    const float* __restrict__ x, const u16* __restrict__ s2wp,
    const u16* __restrict__ w1p, const float* __restrict__ cb,
    const int* __restrict__ stage, u16* __restrict__ o1)
{
    __shared__ __align__(16) u16 lds[LDSZ];
    const int b = blockIdx.x, t = threadIdx.x;
    const int wv = t >> 6, lane = t & 63, lr = lane & 15, q = lane >> 4;

    uint* zi = (uint*)lds;
    for (int i = t; i < 3488; i += 256) zi[i] = 0u;
    for (int i = t; i < 864; i += 256)
        *(short8v*)(&lds[S2W + i * 8]) = *(const short8v*)(&s2wp[i * 8]);
    for (int i = t; i < 288; i += 256)
        *(short8v*)(&lds[W1L + i * 8]) = *(const short8v*)(&w1p[i * 8]);

    const int sv = stage[0];
    if (sv == 2) {
        {
            const int n = t >> 2, ir = t & 3;
            const float* xp = x + (size_t)b * 3072 + (((n >> 3) * 4 + ir) * 96 + (n & 7) * 12);
            const float4 va = ((const float4*)xp)[0];
            const float4 vb = ((const float4*)xp)[1];
            const float4 vc = ((const float4*)xp)[2];
            uint* dst = (uint*)&lds[XB + n * 72 + ir * 12];
            dst[0] = pk2(va.x, va.y); dst[1] = pk2(va.z, va.w);
            dst[2] = pk2(vb.x, vb.y); dst[3] = pk2(vb.z, vb.w);
            dst[4] = pk2(vc.x, vc.y); dst[5] = pk2(vc.z, vc.w);
            if (ir < 2) {
                uint* z2 = (uint*)&lds[XB + n * 72 + 48 + ir * 8];
                z2[0] = 0u; z2[1] = 0u; z2[2] = 0u; z2[3] = 0u;
            }
        }
        __syncthreads();
        short8v a0 = *(const short8v*)&lds[XB + (wv * 16 + lr) * 72 + q * 8];
        short8v a1 = *(const short8v*)&lds[XB + (wv * 16 + lr) * 72 + 32 + q * 8];
        f32x4 y[3];
        #pragma unroll
        for (int nf = 0; nf < 3; ++nf) {
            y[nf] = (f32x4){0.f, 0.f, 0.f, 0.f};
            short8v bh0 = *(const short8v*)&lds[S2W + (nf * 16 + lr) * 72 + q * 8];
            short8v bh1 = *(const short8v*)&lds[S2W + (nf * 16 + lr) * 72 + 32 + q * 8];
            short8v bl0 = *(const short8v*)&lds[S2W + (48 + nf * 16 + lr) * 72 + q * 8];
            short8v bl1 = *(const short8v*)&lds[S2W + (48 + nf * 16 + lr) * 72 + 32 + q * 8];
            y[nf] = __builtin_amdgcn_mfma_f32_16x16x32_bf16(a0, bh0, y[nf], 0, 0, 0);
            y[nf] = __builtin_amdgcn_mfma_f32_16x16x32_bf16(a1, bh1, y[nf], 0, 0, 0);
            y[nf] = __builtin_amdgcn_mfma_f32_16x16x32_bf16(a0, bl0, y[nf], 0, 0, 0);
            y[nf] = __builtin_amdgcn_mfma_f32_16x16x32_bf16(a1, bl1, y[nf], 0, 0, 0);
        }
        __syncthreads();
        #pragma unroll
        for (int nf = 0; nf < 3; ++nf)
            #pragma unroll
            for (int r = 0; r < 4; ++r) {
                int n2 = wv * 16 + q * 4 + r;
                int o  = nf * 16 + lr;
                int ir = o / 12, rm = o - ir * 12;
                int jc = rm / 3, c = rm - jc * 3;
                int hh = (n2 >> 3) * 4 + ir, ww = (n2 & 7) * 4 + jc;
                int e  = ((hh + 1) * 34 + (ww + 1)) * 3 + c;
                u16 val = f2bu(y[nf][r]);
                lds[IMG_E + e] = val;
                lds[IMG_O + e - 1] = val;
            }
    } else {
        __syncthreads();
        for (int e = t; e < 3072; e += 256) {
            int hh = e / 96, rm = e - hh * 96;
            int ww = rm / 3, c = rm - ww * 3;
            u16 val = f2bu(x[(size_t)b * 3072 + e]);
            int ii = ((hh + 1) * 34 + (ww + 1)) * 3 + c;
            lds[IMG_E + ii] = val;
            lds[IMG_O + ii - 1] = val;
        }
    }
    __syncthreads();

    short8v wf[2][2];
    #pragma unroll
    for (int nf = 0; nf < 2; ++nf)
        #pragma unroll
        for (int ks = 0; ks < 2; ++ks)
            wf[nf][ks] = *(const short8v*)&lds[W1L + (nf * 16 + lr) * 72 + ks * 32 + q * 8];
    const float bias[2] = {cb[lr], cb[16 + lr]};
    u16* op = o1 + (size_t)b * 8192;

    #pragma unroll
    for (int mc = 0; mc < 4; ++mc) {
        f32x4 acc[4][2];
        #pragma unroll
        for (int mi = 0; mi < 4; ++mi)
            #pragma unroll
            for (int nf = 0; nf < 2; ++nf) acc[mi][nf] = (f32x4){0.f, 0.f, 0.f, 0.f};
        #pragma unroll
        for (int mi = 0; mi < 4; ++mi) {
            const int p = wv * 256 + (mc * 4 + mi) * 16 + lr;
            const int ph = p >> 5, pw = p & 31;
            #pragma unroll
            for (int ks = 0; ks < 2; ++ks) {
                const int r = ks ? 2 : (q >> 1);
                const int a = 3 * ((ph + r) * 34 + pw) + (q & 1) * 8;
                const uint* sp = (a & 1) ? (const uint*)&lds[IMG_O + a - 1]
                                         : (const uint*)&lds[IMG_E + a];
                pack8 pk;
                pk.u[0] = sp[0]; pk.u[1] = sp[1]; pk.u[2] = sp[2]; pk.u[3] = sp[3];
                acc[mi][0] = __builtin_amdgcn_mfma_f32_16x16x32_bf16(pk.v, wf[0][ks], acc[mi][0], 0, 0, 0);
                acc[mi][1] = __builtin_amdgcn_mfma_f32_16x16x32_bf16(pk.v, wf[1][ks], acc[mi][1], 0, 0, 0);
            }
        }
        #pragma unroll
        for (int pr = 0; pr < 2; ++pr)
            #pragma unroll
            for (int nf = 0; nf < 2; ++nf) {
                const float bb = bias[nf];
                #pragma unroll
                for (int j = 0; j < 2; ++j) {
                    float v = fmaxf(acc[pr][nf][2 * j] + bb, 0.f);
                    v = fmaxf(v, fmaxf(acc[pr][nf][2 * j + 1] + bb, 0.f));
                    v = fmaxf(v, fmaxf(acc[pr + 2][nf][2 * j] + bb, 0.f));
                    v = fmaxf(v, fmaxf(acc[pr + 2][nf][2 * j + 1] + bb, 0.f));
                    const int hq = wv * 4 + mc, wq = pr * 8 + q * 2 + j;
                    op[(hq * 16 + wq) * 32 + nf * 16 + lr] = f2bu(v);
                }
            }
    }
}

// ---------------------------------------------------------------------------
// K3: conv2 32->64 + ReLU + maxpool2, MFMA implicit GEMM.
// v2: weights from global (L2-hot, 37.9 KB set), depth-2 prefetch; LDS = input
// tile only (25.9 KB) -> ~6 blocks/CU by LDS, 3 waves/SIMD by VGPR.
// ---------------------------------------------------------------------------
__global__ __launch_bounds__(256) void k_conv2m(
    const u16* __restrict__ o1, const u16* __restrict__ w2p,
    const float* __restrict__ cb, u16* __restrict__ o2)
{
    __shared__ u16 inl[12960];   // ((h)*18+w)*40 + ic ; zero halo
    const int b = blockIdx.x, t = threadIdx.x;
    uint* z = (uint*)inl;
    for (int i = t; i < 6480; i += 256) z[i] = 0u;
    __syncthreads();
    const u16* ip = o1 + (size_t)b * 8192;
    for (int e = t; e < 1024; e += 256) {
        int ic8 = e & 3, w = (e >> 2) & 15, h = e >> 6;
        *(short8v*)(&inl[((h + 1) * 18 + (w + 1)) * 40 + ic8 * 8]) =
            *(const short8v*)(&ip[e * 8]);
    }
    __syncthreads();
    const int wv = t >> 6, lane = t & 63;
    const int lr = lane & 15, q = lane >> 4;
    // per-lane weight base: row = n*16 + lr, col = tap*32 + q*8
    const u16* wb = w2p + (size_t)lr * 296 + q * 8;

    f32x4 acc[4][4];
    #pragma unroll
    for (int m = 0; m < 4; ++m)
        #pragma unroll
        for (int n = 0; n < 4; ++n) acc[m][n] = (f32x4){0.f, 0.f, 0.f, 0.f};

    // B-frag pipeline, depth 2, rotating triple buffer (statically indexed).
    short8v bfr[3][4];
    #pragma unroll
    for (int n = 0; n < 4; ++n) {
        bfr[0][n] = *(const short8v*)(wb + n * (16 * 296) + 0);
        bfr[1][n] = *(const short8v*)(wb + n * (16 * 296) + 32);
    }
    #pragma unroll
    for (int s = 0; s < 9; ++s) {
        if (s + 2 < 9) {
            #pragma unroll
            for (int n = 0; n < 4; ++n)
                bfr[(s + 2) % 3][n] = *(const short8v*)(wb + n * (16 * 296) + (s + 2) * 32);
        }
        const int kh = s / 3, kw = s - kh * 3;
        short8v af[4];
        #pragma unroll
        for (int m = 0; m < 4; ++m)
            af[m] = *(const short8v*)(&inl[((wv * 4 + m + kh) * 18 + lr + kw) * 40 + q * 8]);
        #pragma unroll
        for (int m = 0; m < 4; ++m)
            #pragma unroll
            for (int n = 0; n < 4; ++n)
                acc[m][n] = __builtin_amdgcn_mfma_f32_16x16x32_bf16(af[m], bfr[s % 3][n], acc[m][n], 0, 0, 0);
    }
    u16* op = o2 + (size_t)b * 4096;
    #pragma unroll
    for (int n = 0; n < 4; ++n) {
        float bias = cb[n * 16 + lr];
        #pragma unroll
        for (int mp = 0; mp < 2; ++mp) {
            #pragma unroll
            for (int p = 0; p < 2; ++p) {
                float v = fmaxf(acc[2 * mp][n][2 * p] + bias, 0.f);
                v = fmaxf(v, fmaxf(acc[2 * mp][n][2 * p + 1] + bias, 0.f));
                v = fmaxf(v, fmaxf(acc[2 * mp + 1][n][2 * p] + bias, 0.f));
                v = fmaxf(v, fmaxf(acc[2 * mp + 1][n][2 * p + 1] + bias, 0.f));
                int hq = wv * 2 + mp, wq = 2 * q + p;
                op[(hq * 8 + wq) * 64 + n * 16 + lr] = f2bu(v);
            }
        }
    }
}

// ---------------------------------------------------------------------------
// K4: conv3 64->128 + ReLU + maxpool2, MFMA implicit GEMM (global weights,
// depth-2 pipeline; unchanged from round 4).
// ---------------------------------------------------------------------------
__global__ __launch_bounds__(256) void k_conv3m(
    const u16* __restrict__ o2, const u16* __restrict__ w3p,
    const float* __restrict__ cb, u16* __restrict__ o3)
{
    __shared__ u16 inl[28800];   // (u*100 + h*10 + w)*72 + ic ; zero halo
    const int b0 = blockIdx.x * 4, ocb = blockIdx.y * 64, t = threadIdx.x;
    uint* z = (uint*)inl;
    for (int i = t; i < 14400; i += 256) z[i] = 0u;
    __syncthreads();
    for (int e = t; e < 2048; e += 256) {
        int u = e >> 9, rem = e & 511;
        int ic8 = rem & 7, w = (rem >> 3) & 7, h = rem >> 6;
        *(short8v*)(&inl[(u * 100 + (h + 1) * 10 + (w + 1)) * 72 + ic8 * 8]) =
            *(const short8v*)(&o2[(size_t)(b0 + u) * 4096 + rem * 8]);
    }
    __syncthreads();
    const int wv = t >> 6, lane = t & 63;
    const int lr = lane & 15, q = lane >> 4;
    const int hA = lr >> 3, wA = lr & 7;
    const u16* wb = w3p + ((size_t)(ocb + lr)) * 584 + q * 8;

    f32x4 acc[4][4];
    #pragma unroll
    for (int m = 0; m < 4; ++m)
        #pragma unroll
        for (int n = 0; n < 4; ++n) acc[m][n] = (f32x4){0.f, 0.f, 0.f, 0.f};

    short8v bfr[3][4];
    #pragma unroll
    for (int n = 0; n < 4; ++n) {
        bfr[0][n] = *(const short8v*)(wb + n * (16 * 584) + 0);
        bfr[1][n] = *(const short8v*)(wb + n * (16 * 584) + 32);
    }
    #pragma unroll
    for (int s = 0; s < 18; ++s) {
        if (s + 2 < 18) {
            const int off2 = ((s + 2) >> 1) * 64 + ((s + 2) & 1) * 32;
            #pragma unroll
            for (int n = 0; n < 4; ++n)
                bfr[(s + 2) % 3][n] = *(const short8v*)(wb + n * (16 * 584) + off2);
        }
        const int tap = s >> 1, half = s & 1;
        const int kh = tap / 3, kw = tap - kh * 3;
        short8v af[4];
        #pragma unroll
        for (int m = 0; m < 4; ++m)
            af[m] = *(const short8v*)(&inl[(wv * 100 + (m * 2 + hA + kh) * 10 + wA + kw) * 72
                                           + half * 32 + q * 8]);
        #pragma unroll
        for (int m = 0; m < 4; ++m)
            #pragma unroll
            for (int n = 0; n < 4; ++n)
                acc[m][n] = __builtin_amdgcn_mfma_f32_16x16x32_bf16(af[m], bfr[s % 3][n], acc[m][n], 0, 0, 0);
    }
    #pragma unroll
    for (int n = 0; n < 4; ++n) {
        float bias = cb[ocb + n * 16 + lr];
        #pragma unroll
        for (int m = 0; m < 4; ++m) {
            #pragma unroll
            for (int p = 0; p < 2; ++p) {
                float v = fmaxf(acc[m][n][2 * p] + bias, 0.f);
                v = fmaxf(v, fmaxf(acc[m][n][2 * p + 1] + bias, 0.f));
                float v2 = fmaxf(v, __shfl_xor(v, 32));
                if (lane < 32) {
                    int wq = (q & 1) * 2 + p;
                    o3[(size_t)(b0 + wv) * 2048 + (m * 4 + wq) * 128 + ocb + n * 16 + lr] = f2bu(v2);
                }
            }
        }
    }
}

// ---------------------------------------------------------------------------
// K5: fc (2048->10, NCHW flatten) + log_softmax. One wave/image.
// ---------------------------------------------------------------------------
__global__ __launch_bounds__(256) void k_fc(
    const u16* __restrict__ o3, const float* __restrict__ fw,
    const float* __restrict__ fb, float* __restrict__ out)
{
    const int b = blockIdx.x * 4 + (threadIdx.x >> 6);
    const int lane = threadIdx.x & 63;
    const u16* xp = o3 + (size_t)b * 2048;
    float xr[32];
    #pragma unroll
    for (int i = 0; i < 32; ++i) {
        int kk = lane + i * 64;
        int c = kk >> 4, h = (kk >> 2) & 3, w = kk & 3;
        xr[i] = bu2f(xp[h * 512 + w * 128 + c]);
    }
    float lg[10];
    #pragma unroll
    for (int o = 0; o < 10; ++o) {
        const float* wr = fw + (size_t)o * 2048;
        float s = 0.f;
        #pragma unroll
        for (int i = 0; i < 32; ++i) s += xr[i] * wr[lane + i * 64];
        #pragma unroll
        for (int d = 32; d > 0; d >>= 1) s += __shfl_xor(s, d);
        lg[o] = s + fb[o];
    }
    float m = lg[0];
    #pragma unroll
    for (int o = 1; o < 10; ++o) m = fmaxf(m, lg[o]);
    float den = 0.f;
    #pragma unroll
    for (int o = 0; o < 10; ++o) den += expf(lg[o] - m);
    float lse = logf(den);
    if (lane < 10) {
        float v = lg[0];
        #pragma unroll
        for (int o = 1; o < 10; ++o) v = (lane == o) ? lg[o] : v;
        out[(size_t)b * 10 + lane] = v - m - lse;
    }
}

extern "C" void kernel_launch(void* const* d_in, const int* in_sizes, int n_in,
                              void* d_out, int out_size, void* d_ws, size_t ws_size,
                              hipStream_t stream)
{
    const float* x    = (const float*)d_in[0];
    const float* Wlin = (const float*)d_in[1];
    const float* c1w  = (const float*)d_in[2];
    const float* c1b  = (const float*)d_in[3];
    const float* c2w  = (const float*)d_in[4];
    const float* c2b  = (const float*)d_in[5];
    const float* c3w  = (const float*)d_in[6];
    const float* c3b  = (const float*)d_in[7];
    const float* fw   = (const float*)d_in[8];
    const float* fb   = (const float*)d_in[9];
    const int* stage  = (const int*)d_in[10];
    float* out = (float*)d_out;

    const int B = in_sizes[0] / 3072;      // 8192

    char* ws = (char*)d_ws;
    u16* o1   = (u16*)ws;
    u16* o2   = (u16*)(ws + (size_t)B * 16384);
    u16* o3   = (u16*)(ws + (size_t)B * 24576);
    char* WB  = ws + (size_t)B * 28672;
    u16* w1p  = (u16*)(WB);
    u16* s2wp = (u16*)(WB + 4608);
    u16* w2p  = (u16*)(WB + 18432);
    u16* w3p  = (u16*)(WB + 56320);

    k_repack<<<288, 256, 0, stream>>>(Wlin, c1w, c2w, c3w, w1p, s2wp, w2p, w3p);
    k_front <<<B, 256, 0, stream>>>(x, s2wp, w1p, c1b, stage, o1);
    k_conv2m<<<B, 256, 0, stream>>>(o1, w2p, c2b, o2);
    k_conv3m<<<dim3(B / 4, 2), 256, 0, stream>>>(o2, w3p, c3b, o3);
    k_fc    <<<B / 4, 256, 0, stream>>>(o3, fw, fb, out);
}